// Round 2
// baseline (1817.652 us; speedup 1.0000x reference)
//
#include <hip/hip_runtime.h>
#include <hip/hip_bf16.h>
#include <math.h>

// Problem dims (fixed)
#define TT   64
#define BBATCH 64
#define NTOK 64
#define DDIM 128
#define HIDN 256
#define BN   4096     // BBATCH*NTOK

typedef short bf16x8 __attribute__((ext_vector_type(8)));
typedef float f32x4  __attribute__((ext_vector_type(4)));

// ---------------------------------------------------------------------------
// G = C_low^T C_low : symmetric 64x64 Gram of the first 16 orthonormal DCT-II
// rows. lowpass_time(x) == G @ x along time.
// ---------------------------------------------------------------------------
__global__ void k_gram(float* __restrict__ G) {
  int s = blockIdx.x, t = threadIdx.x;
  double acc = 0.0;
  for (int k = 0; k < 16; ++k) {
    double ct, cs;
    if (k == 0) { ct = 0.125; cs = 0.125; }  // sqrt(1/64)
    else {
      const double f = 0.17677669529663687;  // sqrt(2/64)
      ct = cos(M_PI * (t + 0.5) * k / 64.0) * f;
      cs = cos(M_PI * (s + 0.5) * k / 64.0) * f;
    }
    acc += ct * cs;
  }
  G[s * 64 + t] = (float)acc;
}

// ---------------------------------------------------------------------------
// xlp[t,bn,:] = sum_s G[t,s] * M[s,:],  M[s,:] = x[s,bn,:]*(0.05*mx+0.95*mx).
// GEMM-style register tiling: 256 threads, per-thread 4x8 tile, dual
// accumulators (s 0..31 then 32..63, summed at the end — bit-exact match of
// the previous two-half reduction). G in LDS stride 68 (one b128 per step),
// M in LDS stride 128 (two b128). LDS-bound right at the memory floor.
// ---------------------------------------------------------------------------
__global__ __launch_bounds__(256) void k_lowpass(
    const float* __restrict__ x, const float* __restrict__ mx,
    const float* __restrict__ G, float* __restrict__ xlp) {
  __shared__ float Gl[64 * 68];
  __shared__ float Ml[64 * 128];
  const int bn = blockIdx.x;
  const int b = bn >> 6, n = bn & 63;
  // stage G (once per block; L2-cached)
#pragma unroll
  for (int i = 0; i < 4; ++i) {
    int idx4 = threadIdx.x + i * 256;          // 0..1023 float4s
    int s = idx4 >> 4, tq = (idx4 & 15) * 4;
    *(float4*)&Gl[s * 68 + tq] = *(const float4*)&G[s * 64 + tq];
  }
  // stage M = x * mix(mx)
  const float* mxs = mx + (size_t)(n * 64 + b) * 8192;  // (n,b) slab
#pragma unroll
  for (int i = 0; i < 8; ++i) {
    int idx4 = threadIdx.x + i * 256;          // 0..2047 float4s
    int s = idx4 >> 5, dq = (idx4 & 31) * 4;
    const float4 xv = *(const float4*)&x[(size_t)(s * 4096 + bn) * 128 + dq];
    const float4 mv = *(const float4*)&mxs[idx4 * 4];
    float4 r;
    {
#pragma clang fp contract(off)
      r.x = xv.x * (0.05f * mv.x + 0.95f * mv.x);
      r.y = xv.y * (0.05f * mv.y + 0.95f * mv.y);
      r.z = xv.z * (0.05f * mv.z + 0.95f * mv.z);
      r.w = xv.w * (0.05f * mv.w + 0.95f * mv.w);
    }
    *(float4*)&Ml[s * 128 + dq] = r;
  }
  __syncthreads();
  const int mq = threadIdx.x >> 4;   // 0..15: rows t = mq*4+i
  const int ng = threadIdx.x & 15;   // cols ng*8..+7
  float accA[4][8], accB[4][8];
#pragma unroll
  for (int i = 0; i < 4; ++i)
#pragma unroll
    for (int j = 0; j < 8; ++j) { accA[i][j] = 0.f; accB[i][j] = 0.f; }
#pragma unroll 8
  for (int s = 0; s < 32; ++s) {
    float av[4]; *(float4*)av = *(const float4*)&Gl[s * 68 + mq * 4];
    float bv[8];
    *(float4*)&bv[0] = *(const float4*)&Ml[s * 128 + ng * 8];
    *(float4*)&bv[4] = *(const float4*)&Ml[s * 128 + ng * 8 + 4];
#pragma unroll
    for (int i = 0; i < 4; ++i)
#pragma unroll
      for (int j = 0; j < 8; ++j) accA[i][j] = fmaf(av[i], bv[j], accA[i][j]);
  }
#pragma unroll 8
  for (int s = 32; s < 64; ++s) {
    float av[4]; *(float4*)av = *(const float4*)&Gl[s * 68 + mq * 4];
    float bv[8];
    *(float4*)&bv[0] = *(const float4*)&Ml[s * 128 + ng * 8];
    *(float4*)&bv[4] = *(const float4*)&Ml[s * 128 + ng * 8 + 4];
#pragma unroll
    for (int i = 0; i < 4; ++i)
#pragma unroll
      for (int j = 0; j < 8; ++j) accB[i][j] = fmaf(av[i], bv[j], accB[i][j]);
  }
#pragma unroll
  for (int i = 0; i < 4; ++i) {
    int t = mq * 4 + i;
    float4 o0, o1;
    o0.x = accA[i][0] + accB[i][0]; o0.y = accA[i][1] + accB[i][1];
    o0.z = accA[i][2] + accB[i][2]; o0.w = accA[i][3] + accB[i][3];
    o1.x = accA[i][4] + accB[i][4]; o1.y = accA[i][5] + accB[i][5];
    o1.z = accA[i][6] + accB[i][6]; o1.w = accA[i][7] + accB[i][7];
    size_t base = (size_t)(t * 4096 + bn) * 128 + ng * 8;
    *(float4*)&xlp[base] = o0;
    *(float4*)&xlp[base + 4] = o1;
  }
}

// ---------------------------------------------------------------------------
// Fused GEMM + LIF (+ optional gate). 128 threads, per-thread 8x8 tile.
// A tile (64t x 64k) in LDS [k][t] stride 66 (staging writes 4-way, inner
// reads 4x ds_read_b64, 2-way = free). B (weights) read straight from global
// each k-step: W is 64 KB shared by all 4096 blocks -> L1/L2 resident; this
// takes B off the CU's LDS pipe entirely -> inner loop is VALU-bound.
// fmaf order over ascending k is IDENTICAL to the previous passing kernel
// -> bit-identical pre-activations -> identical spikes.
// ---------------------------------------------------------------------------
template <int KDIM, bool ABF16, bool GATE>
__global__ __launch_bounds__(128) void k_gemm_lif(
    const void* __restrict__ Ap, const float* __restrict__ W, const int NW,
    const float* __restrict__ gate, void* __restrict__ outp) {
  __shared__ float Al[64 * 66];   // 16.9 KB; reused as C tile per col-half
  const int bn = blockIdx.x;
  const int c0 = blockIdx.y * 128;
  const int tid = threadIdx.x;
  const int mq = tid >> 4;        // 0..7 : rows t = mq*8 + i
  const int ng = tid & 15;        // cols ng*8..+7
  float acc[8][8];
#pragma unroll
  for (int i = 0; i < 8; ++i)
#pragma unroll
    for (int j = 0; j < 8; ++j) acc[i][j] = 0.f;

  const float* Wp = W + (size_t)c0 + ng * 8;
  for (int kc = 0; kc < KDIM; kc += 64) {
    {  // stage A chunk: lane = k (coalesced 256B rows), 32 t-rows per thread
      const int k = tid & 63, th = tid >> 6;
      const size_t rstep = (size_t)4096 * KDIM;
      size_t ra = (size_t)(th * 32 * 4096 + bn) * KDIM + kc + k;
      int la = k * 66 + th * 32;
#pragma unroll 8
      for (int i = 0; i < 32; ++i) {
        float v;
        if (ABF16) {
          unsigned short bits = ((const unsigned short*)Ap)[ra];
          v = __uint_as_float((unsigned)bits << 16);
        } else {
          v = ((const float*)Ap)[ra];
        }
        Al[la + i] = v;
        ra += rstep;
      }
    }
    __syncthreads();
    const float* Wk = Wp + (size_t)kc * NW;
#pragma unroll 8
    for (int k2 = 0; k2 < 64; ++k2) {
      float bv[8];
      *(float4*)&bv[0] = *(const float4*)&Wk[(size_t)k2 * NW];
      *(float4*)&bv[4] = *(const float4*)&Wk[(size_t)k2 * NW + 4];
      float av[8];
      const float* Ar = &Al[k2 * 66 + mq * 8];
      *(float2*)&av[0] = *(const float2*)&Ar[0];
      *(float2*)&av[2] = *(const float2*)&Ar[2];
      *(float2*)&av[4] = *(const float2*)&Ar[4];
      *(float2*)&av[6] = *(const float2*)&Ar[6];
#pragma unroll
      for (int i = 0; i < 8; ++i)
#pragma unroll
        for (int j = 0; j < 8; ++j) acc[i][j] = fmaf(av[i], bv[j], acc[i][j]);
    }
    __syncthreads();
  }
  // Epilogue: two column-halves through the reused 64x66 LDS tile, LIF scan.
  float* Cl = Al;
  for (int h = 0; h < 2; ++h) {
    if ((ng >> 3) == h) {
      const int ng2 = ng & 7;
#pragma unroll
      for (int i = 0; i < 8; ++i) {
        int t = mq * 8 + i;
#pragma unroll
        for (int w = 0; w < 4; ++w) {
          *(float2*)&Cl[t * 66 + ng2 * 8 + 2 * w] =
              make_float2(acc[i][2 * w], acc[i][2 * w + 1]);
        }
      }
    }
    __syncthreads();
    if (tid < 64) {
      const int c = h * 64 + tid;
      float v = 0.f;
      for (int t = 0; t < 64; ++t) {
        float pre = Cl[t * 66 + tid];
        {
#pragma clang fp contract(off)
          float dlt = (pre - v) * 0.5f;  // v + (c-v)/tau, tau=2
          v = v + dlt;
        }
        bool s = (v >= 1.0f);
        size_t orow = (size_t)(t * 4096 + bn);
        if (GATE) {
          float g = gate[orow * 128 + c];
          ((float*)outp)[orow * 128 + c] = s ? 0.f : g;  // g*(1-s) exact
        } else {
          ((unsigned short*)outp)[orow * NW + c0 + c] =
              s ? (unsigned short)0x3F80 : (unsigned short)0;
        }
        v = s ? 0.f : v;  // hard reset
      }
    }
    __syncthreads();
  }
}

// ---------------------------------------------------------------------------
// Spiking 2-head attention per (t,b):  S = q k^T * 0.125 ; O = S v.
// Exact in bf16 MFMA (spikes in {0,1}; S integer<=64; O multiples of 1/8).
// ---------------------------------------------------------------------------
__global__ __launch_bounds__(256) void k_attn(
    const unsigned short* __restrict__ q, const unsigned short* __restrict__ kk,
    const unsigned short* __restrict__ vv, float* __restrict__ o) {
  __shared__ unsigned short ql[64 * 136];  // [n][d] bf16 bits
  __shared__ unsigned short kl[64 * 136];
  __shared__ unsigned short vt[128 * 72];  // [d][m] (v transposed)
  __shared__ unsigned short sl[64 * 72];   // S' [n][m] per head (reused)
  const size_t base = (size_t)blockIdx.x * 8192;
#pragma unroll
  for (int i = 0; i < 4; ++i) {
    int idx8 = threadIdx.x + i * 256;     // 1024 x 8-elem chunks
    int n = idx8 >> 4, d8 = (idx8 & 15) * 8;
    uint4 pq = *(const uint4*)&q[base + n * 128 + d8];
    uint4 pk = *(const uint4*)&kk[base + n * 128 + d8];
    *(uint4*)&ql[n * 136 + d8] = pq;
    *(uint4*)&kl[n * 136 + d8] = pk;
    uint4 pv = *(const uint4*)&vv[base + n * 128 + d8];
    unsigned short e[8] = {
        (unsigned short)(pv.x & 0xFFFF), (unsigned short)(pv.x >> 16),
        (unsigned short)(pv.y & 0xFFFF), (unsigned short)(pv.y >> 16),
        (unsigned short)(pv.z & 0xFFFF), (unsigned short)(pv.z >> 16),
        (unsigned short)(pv.w & 0xFFFF), (unsigned short)(pv.w >> 16)};
#pragma unroll
    for (int j = 0; j < 8; ++j) vt[(d8 + j) * 72 + n] = e[j];
  }
  __syncthreads();
  const int lane = threadIdx.x & 63;
  const int w = threadIdx.x >> 6;          // wave id = n-tile (ti)
  const int l15 = lane & 15, l4 = lane >> 4;
  for (int h = 0; h < 2; ++h) {
    bf16x8 af0 = *(const bf16x8*)&ql[(w * 16 + l15) * 136 + h * 64 + l4 * 8];
    bf16x8 af1 = *(const bf16x8*)&ql[(w * 16 + l15) * 136 + h * 64 + 32 + l4 * 8];
#pragma unroll
    for (int tj = 0; tj < 4; ++tj) {
      f32x4 c = {0.f, 0.f, 0.f, 0.f};
      bf16x8 b0 = *(const bf16x8*)&kl[(tj * 16 + l15) * 136 + h * 64 + l4 * 8];
      c = __builtin_amdgcn_mfma_f32_16x16x32_bf16(af0, b0, c, 0, 0, 0);
      bf16x8 b1 = *(const bf16x8*)&kl[(tj * 16 + l15) * 136 + h * 64 + 32 + l4 * 8];
      c = __builtin_amdgcn_mfma_f32_16x16x32_bf16(af1, b1, c, 0, 0, 0);
#pragma unroll
      for (int r = 0; r < 4; ++r) {
        float sp = c[r] * 0.125f;  // exact
        sl[(w * 16 + l4 * 4 + r) * 72 + tj * 16 + l15] =
            (unsigned short)(__float_as_uint(sp) >> 16);
      }
    }
    __syncthreads();
    bf16x8 a20 = *(const bf16x8*)&sl[(w * 16 + l15) * 72 + l4 * 8];
    bf16x8 a21 = *(const bf16x8*)&sl[(w * 16 + l15) * 72 + 32 + l4 * 8];
#pragma unroll
    for (int tj = 0; tj < 4; ++tj) {
      f32x4 c = {0.f, 0.f, 0.f, 0.f};
      bf16x8 b0 = *(const bf16x8*)&vt[(h * 64 + tj * 16 + l15) * 72 + l4 * 8];
      c = __builtin_amdgcn_mfma_f32_16x16x32_bf16(a20, b0, c, 0, 0, 0);
      bf16x8 b1 = *(const bf16x8*)&vt[(h * 64 + tj * 16 + l15) * 72 + 32 + l4 * 8];
      c = __builtin_amdgcn_mfma_f32_16x16x32_bf16(a21, b1, c, 0, 0, 0);
#pragma unroll
      for (int r = 0; r < 4; ++r)
        o[base + (size_t)(w * 16 + l4 * 4 + r) * 128 + h * 64 + tj * 16 + l15] = c[r];
    }
    __syncthreads();
  }
}

// ---------------------------------------------------------------------------
extern "C" void kernel_launch(void* const* d_in, const int* in_sizes, int n_in,
                              void* d_out, int out_size, void* d_ws, size_t ws_size,
                              hipStream_t stream) {
  const float* x  = (const float*)d_in[0];
  const float* mx = (const float*)d_in[1];
  const float* Wq = (const float*)d_in[2];
  const float* Wk = (const float*)d_in[3];
  const float* Wv = (const float*)d_in[4];
  const float* Wo = (const float*)d_in[5];
  const float* W1 = (const float*)d_in[6];
  const float* W2 = (const float*)d_in[7];
  float* out = (float*)d_out;

  char* w = (char*)d_ws;
  float* G   = (float*)w;                                   // 16 KB (pad 64K)
  float* xlp = (float*)(w + 65536);                         // 134 MB, later o
  float* x2  = (float*)(w + 65536 + 134217728ull);          // 134 MB
  unsigned short* sq = (unsigned short*)(w + 65536 + 268435456ull);  // 67 MB
  unsigned short* sk = sq + 33554432ull;                    // 67 MB
  unsigned short* sv = sk + 33554432ull;                    // 67 MB
  unsigned short* sh = sq;  // mlp hidden spikes overlay sq+sk (134 MB)

  k_gram<<<64, 64, 0, stream>>>(G);
  k_lowpass<<<4096, 256, 0, stream>>>(x, mx, G, xlp);
  // q from x; k,v from lowpassed memory stream
  k_gemm_lif<128, false, false><<<dim3(4096, 1), 128, 0, stream>>>(x,   Wq, 128, nullptr, sq);
  k_gemm_lif<128, false, false><<<dim3(4096, 1), 128, 0, stream>>>(xlp, Wk, 128, nullptr, sk);
  k_gemm_lif<128, false, false><<<dim3(4096, 1), 128, 0, stream>>>(xlp, Wv, 128, nullptr, sv);
  k_attn<<<4096, 256, 0, stream>>>(sq, sk, sv, xlp);  // o overwrites xlp
  // attn_spk = lif(o @ Wo); x2 = x * (1 - attn_spk)
  k_gemm_lif<128, false, true ><<<dim3(4096, 1), 128, 0, stream>>>(xlp, Wo, 128, x, x2);
  // mlp: h = lif(x2 @ W1); out = x2 * (1 - lif(h @ W2))
  k_gemm_lif<128, false, false><<<dim3(4096, 2), 128, 0, stream>>>(x2, W1, 256, nullptr, sh);
  k_gemm_lif<256, true,  true ><<<dim3(4096, 1), 128, 0, stream>>>(sh, W2, 128, x2, out);
}